// Round 2
// baseline (511.379 us; speedup 1.0000x reference)
//
#include <hip/hip_runtime.h>

// Complete K=8-ary tree, DEPTH=5.
// Level starts: L0:0, L1:1, L2:9, L3:73, L4:585, leaves:4681..37448.
constexpr int NUM_NODES = 37449;
constexpr int L5 = 4681;   // leaf start (32768 leaves)
constexpr int L4 = 585;    // 4096 nodes
constexpr int L3 = 73;     // 512 nodes
constexpr int L2 = 9;      // 64 nodes
constexpr int L1 = 1;      // 8 nodes
constexpr int NLEAF = 32768;

__global__ void sigw_kernel(const float* __restrict__ w, float* __restrict__ sigw) {
    int i = blockIdx.x * blockDim.x + threadIdx.x;
    if (i < NUM_NODES) sigw[i] = 1.0f / (1.0f + __expf(-w[i]));
}

__device__ __forceinline__ float clamp01(float x) {
    return fminf(fmaxf(x, 0.0f), 1.0f);
}

// 16B vector ops valid at ANY 4B-aligned address (gfx950 unaligned-access-mode;
// hardware-proven by the previous passing round, where memcpy lowered to
// global_load/store_dwordx4 at 4B alignment). The packed,aligned(4) wrapper
// makes clang emit <4 x float> accesses with align 4. nontemporal variants set
// the `nt` cache-policy bit: the 575 MB leaf/out stream has ZERO reuse, so
// streaming it past L2 keeps the (reused, 150 KB) sigw table resident.
typedef float f32x4 __attribute__((ext_vector_type(4)));
struct __attribute__((packed, aligned(4))) F4un { f32x4 v; };

__device__ __forceinline__ f32x4 ld4_nt(const float* __restrict__ p) {
    return __builtin_nontemporal_load(&((const F4un*)p)->v);
}
__device__ __forceinline__ f32x4 ld4(const float* __restrict__ p) {
    return ((const F4un*)p)->v;   // default (cached) policy — for sigw
}
__device__ __forceinline__ void st4_nt(float* __restrict__ p, f32x4 v) {
    __builtin_nontemporal_store(v, &((F4un*)p)->v);
}

// One block per batch row. Leaves streamed as float4 (16B/lane, coalesced, nt);
// pairs of lanes own one 8-leaf parent: per-lane dot4, one shfl_xor(1).
// Reduction association matches the original 3-step butterfly exactly:
// ((p0+p1)+(p2+p3)) + ((p4+p5)+(p6+p7)).
__global__ __launch_bounds__(256, 8)
void tree_kernel(const float* __restrict__ in, const float* __restrict__ sigw,
                 float* __restrict__ out) {
    __shared__ float l4s[4096];
    __shared__ float l3s[512];
    __shared__ float l2s[64];
    __shared__ float l1s[8];

    const int t = threadIdx.x;
    const size_t base = (size_t)blockIdx.x * NUM_NODES;
    const float* __restrict__ rin = in + base;
    float* __restrict__ rout = out + base;

    // Stage 1: leaves -> level-4; pass-through copy of leaves (nt both ways).
    // 32768 leaves = 8192 float4 chunks; 256 threads -> 32 iterations.
    #pragma unroll 4
    for (int i = 0; i < 32; ++i) {
        const int v = i * 256 + t;      // float4 chunk id in [0, 8192)
        const int e = v << 2;           // leaf element index (multiple of 4)
        f32x4 d = ld4_nt(rin + L5 + e);
        f32x4 s = ld4(sigw + L5 + e);   // cached: reused by all 2048 blocks
        st4_nt(rout + L5 + e, d);
        float p0 = d.x * s.x;
        float p1 = d.y * s.y;
        float p2 = d.z * s.z;
        float p3 = d.w * s.w;
        float m = (p0 + p1) + (p2 + p3);
        m += __shfl_xor(m, 1);          // pair covers 8 consecutive leaves
        if ((t & 1) == 0) l4s[v >> 1] = clamp01(m);
    }
    __syncthreads();

    // Stage 2: level-4 -> level-3; write level-4 out (vectorized, nt store).
    // 4096 elems = 1024 chunks; 4 iterations.
    #pragma unroll
    for (int i = 0; i < 4; ++i) {
        const int v = i * 256 + t;      // chunk id in [0, 1024)
        const int e = v << 2;
        f32x4 d;                         // contiguous aligned LDS -> ds_read_b128
        d.x = l4s[e + 0];
        d.y = l4s[e + 1];
        d.z = l4s[e + 2];
        d.w = l4s[e + 3];
        f32x4 s = ld4(sigw + L4 + e);
        st4_nt(rout + L4 + e, d);
        float p0 = d.x * s.x;
        float p1 = d.y * s.y;
        float p2 = d.z * s.z;
        float p3 = d.w * s.w;
        float m = (p0 + p1) + (p2 + p3);
        m += __shfl_xor(m, 1);
        if ((t & 1) == 0) l3s[v >> 1] = clamp01(m);
    }
    __syncthreads();

    // Stage 3: level-3 -> level-2; write level-3 out. (512 elems — tiny, scalar.)
    for (int i = t; i < 512; i += 256) {
        float v = l3s[i];
        rout[L3 + i] = v;
        float s = v * sigw[L3 + i];
        s += __shfl_xor(s, 1);
        s += __shfl_xor(s, 2);
        s += __shfl_xor(s, 4);
        if ((i & 7) == 0) l2s[i >> 3] = clamp01(s);
    }
    __syncthreads();

    // Stage 4: level-2 -> level-1; write level-2 out.
    if (t < 64) {
        float v = l2s[t];
        rout[L2 + t] = v;
        float s = v * sigw[L2 + t];
        s += __shfl_xor(s, 1);
        s += __shfl_xor(s, 2);
        s += __shfl_xor(s, 4);
        if ((t & 7) == 0) l1s[t >> 3] = clamp01(s);
    }
    __syncthreads();

    // Stage 5: level-1 -> root; write level-1 out.
    if (t < 8) {
        float v = l1s[t];
        rout[L1 + t] = v;
        float s = v * sigw[L1 + t];
        s += __shfl_xor(s, 1);
        s += __shfl_xor(s, 2);
        s += __shfl_xor(s, 4);
        if (t == 0) rout[0] = clamp01(s);
    }
}

extern "C" void kernel_launch(void* const* d_in, const int* in_sizes, int n_in,
                              void* d_out, int out_size, void* d_ws, size_t ws_size,
                              hipStream_t stream) {
    const float* probs = (const float*)d_in[0];   // [batch, NUM_NODES] fp32
    const float* w     = (const float*)d_in[1];   // [NUM_NODES] fp32
    float* out  = (float*)d_out;
    float* sigw = (float*)d_ws;                   // 37449*4 B = 150 KB scratch

    const int batch = in_sizes[0] / NUM_NODES;    // 2048

    hipLaunchKernelGGL(sigw_kernel, dim3((NUM_NODES + 255) / 256), dim3(256), 0,
                       stream, w, sigw);
    hipLaunchKernelGGL(tree_kernel, dim3(batch), dim3(256), 0, stream,
                       probs, sigw, out);
}